// Round 4
// baseline (290.337 us; speedup 1.0000x reference)
//
#include <hip/hip_runtime.h>
#include <stdint.h>

#define D_IN 128
#define D_OUT 128
#define NREL 8
#define NBASE 4

typedef __attribute__((ext_vector_type(8))) short short8;
typedef __attribute__((ext_vector_type(4))) float floatx4;
typedef __attribute__((ext_vector_type(2))) float floatx2;

__device__ __forceinline__ unsigned short f2bf(float f) {
  unsigned int u = __float_as_uint(f);
  u += 0x7fffu + ((u >> 16) & 1u);
  return (unsigned short)(u >> 16);
}
__device__ __forceinline__ unsigned pack2bf(float lo, float hi) {
  return (unsigned)f2bf(lo) | ((unsigned)f2bf(hi) << 16);
}
__device__ __forceinline__ float bflo(unsigned int u) { return __uint_as_float(u << 16); }
__device__ __forceinline__ float bfhi(unsigned int u) { return __uint_as_float(u & 0xffff0000u); }

// ---------- 1) prep: zero counts + cast X fp32->bf16 + build W2T ----------
// W2T[o][c] = w_bases[b][k][o], c = k*4+b  (bf16, [128][512])
__global__ void k_prep(const float4* __restrict__ X, ushort4* __restrict__ Xb, int n4,
                       const float* __restrict__ w_bases, unsigned short* __restrict__ W2T,
                       uint4* __restrict__ counts4, int nc4) {
  int i = blockIdx.x * blockDim.x + threadIdx.x;
  if (i < n4) {
    float4 v = X[i];
    ushort4 o;
    o.x = f2bf(v.x); o.y = f2bf(v.y); o.z = f2bf(v.z); o.w = f2bf(v.w);
    Xb[i] = o;
  }
  if (i < 128 * 512) {
    int o = i >> 9, c = i & 511;
    int k = c >> 2, b = c & 3;
    W2T[i] = f2bf(w_bases[(b * D_IN + k) * D_OUT + o]);
  }
  if (i < nc4) counts4[i] = make_uint4(0u, 0u, 0u, 0u);
}

// ---------- 2) CSR build ----------
__global__ void k_count(const int* __restrict__ dst, int* __restrict__ counts, int E) {
  int i = blockIdx.x * blockDim.x + threadIdx.x;
  if (i < E) atomicAdd(&counts[dst[i]], 1);
}

__global__ void k_scan1(const int* __restrict__ counts, int* __restrict__ localsc,
                        int* __restrict__ bsum, int Nn) {
  __shared__ int s[256];
  int i = blockIdx.x * 256 + threadIdx.x;
  int v = (i < Nn) ? counts[i] : 0;
  s[threadIdx.x] = v;
  __syncthreads();
  for (int off = 1; off < 256; off <<= 1) {
    int t = 0;
    if (threadIdx.x >= off) t = s[threadIdx.x - off];
    __syncthreads();
    s[threadIdx.x] += t;
    __syncthreads();
  }
  if (i < Nn) localsc[i] = s[threadIdx.x] - v;
  if (threadIdx.x == 255) bsum[blockIdx.x] = s[255];
}

// fused scan2+scan3: each block redundantly reduces bsum[0..blockIdx.x) (tiny)
__global__ void k_scan23(const int* __restrict__ localsc, const int* __restrict__ bsum,
                         int* __restrict__ offsets, int* __restrict__ cursor, int Nn, int E) {
  __shared__ int red[256];
  int acc = 0;
  for (int j = threadIdx.x; j < blockIdx.x; j += 256) acc += bsum[j];
  red[threadIdx.x] = acc;
  __syncthreads();
  for (int off = 128; off > 0; off >>= 1) {
    if (threadIdx.x < off) red[threadIdx.x] += red[threadIdx.x + off];
    __syncthreads();
  }
  int pref = red[0];
  int i = blockIdx.x * 256 + threadIdx.x;
  if (i < Nn) {
    int v = localsc[i] + pref;
    offsets[i] = v;
    cursor[i] = v;
  }
  if (i == 0) offsets[Nn] = E;
}

// compact 8B record: (src | rel<<21, val) — scattered write is 8B not 20B
__global__ void k_bucket(const int* __restrict__ src, const int* __restrict__ dst,
                         const int* __restrict__ rel, const float* __restrict__ val,
                         int* __restrict__ cursor, uint2* __restrict__ bucket, int E) {
  int i = blockIdx.x * blockDim.x + threadIdx.x;
  if (i >= E) return;
  int d = dst[i];
  int pos = atomicAdd(&cursor[d], 1);
  bucket[pos] = make_uint2((unsigned)src[i] | ((unsigned)rel[i] << 21), __float_as_uint(val[i]));
}

// ---------- 3) fused: per-dst basis aggregation (LDS) + MFMA transform ----------
// Block = 2 waves, 16 dst rows (LDS 16.8KB -> ~9 blocks/CU occupancy).
// Wave w owns dsts [w*8, w*8+8) = ONE contiguous bucket range, processed as a flat
// edge stream. Records chunk-loaded cooperatively (64/load, double-buffered in
// VGPRs, distributed via __shfl). DEPTH-4 software pipeline (groups A-D, 16 edges
// in flight) so gather latency (~600cy) is covered by ~3 group bodies.
// Scalar (SGPR) bounds via v_readlane -> s_cmp boundary checks.
__global__ __launch_bounds__(128)
void k_agg_gemm(const uint2* __restrict__ bucket, const int* __restrict__ offsets,
                const float* __restrict__ w_rel_g, const unsigned* __restrict__ Xb2,
                const unsigned short* __restrict__ W2T, float* __restrict__ out, int Nn) {
  __shared__ __align__(16) unsigned short aggS[16][520];  // pitch 520: 2-way alias (free)
  __shared__ __align__(16) float wrS[NREL * NBASE];
  if (threadIdx.x < NREL * NBASE) wrS[threadIdx.x] = w_rel_g[threadIdx.x];
  __syncthreads();

  const int wave = threadIdx.x >> 6, lane = threadIdx.x & 63;
  const int d0 = blockIdx.x * 16 + wave * 8;
  const unsigned* __restrict__ Xl = Xb2 + lane;
  const floatx2 zf2 = {0.f, 0.f};

  // lane l (0..8) loads offsets[d0+l]; readlane -> SGPR bounds
  int oidx = d0 + (lane < 8 ? lane : 8);
  if (oidx > Nn) oidx = Nn;
  const int offv = offsets[oidx];
  const int s0 = __builtin_amdgcn_readlane(offv, 0);
  const int e8 = __builtin_amdgcn_readlane(offv, 8);

  floatx2 a0 = zf2, a1 = zf2, a2 = zf2, a3 = zf2;
  int row = 0;
  int bnd = __builtin_amdgcn_readlane(offv, 1);

#define FLUSH()                                                      \
  do {                                                               \
    uint4 o_;                                                        \
    o_.x = pack2bf(a0.x, a1.x);                                      \
    o_.y = pack2bf(a2.x, a3.x);                                      \
    o_.z = pack2bf(a0.y, a1.y);                                      \
    o_.w = pack2bf(a2.y, a3.y);                                      \
    *(uint4*)&aggS[wave * 8 + row][lane * 8] = o_;                   \
    a0 = zf2; a1 = zf2; a2 = zf2; a3 = zf2;                          \
    ++row;                                                           \
    bnd = (row < 8) ? __builtin_amdgcn_readlane(offv, row + 1)       \
                    : 0x7fffffff;                                    \
  } while (0)

  // ACCT: R = packed (src|rel<<21), V = val bits, Y = gathered 2xbf16
#define ACCT(EI, R, V, Y)                                            \
  do {                                                               \
    if ((EI) < e8) {                                                 \
      while ((EI) == bnd) FLUSH();                                   \
      const float4 w_ = *(const float4*)&wrS[((R) >> 21) * 4];       \
      const float val_ = __uint_as_float(V);                         \
      const float c0_ = val_ * w_.x, c1_ = val_ * w_.y;              \
      const float c2_ = val_ * w_.z, c3_ = val_ * w_.w;              \
      floatx2 x_;                                                    \
      x_.x = bflo(Y);                                                \
      x_.y = bfhi(Y);                                                \
      a0 += c0_ * x_;                                                \
      a1 += c1_ * x_;                                                \
      a2 += c2_ * x_;                                                \
      a3 += c3_ * x_;                                                \
    }                                                                \
  } while (0)

  // LOADG: rotate chunk if needed, shuffle 4 records out, issue 4 gathers.
  // All indices clamped to ce so over-issue past e8 is safe (ACCT guards).
  // Invariant: group bases === s0 (mod 4), chunk bounds === s0 (mod 64)
  // -> a group never straddles a chunk.
#define LOADG(P, BASE)                                               \
  do {                                                               \
    int t0_ = (BASE); if (t0_ > ce) t0_ = ce;                        \
    if (t0_ - cbase >= 64) {                                         \
      cbase += 64;                                                   \
      chC = chN;                                                     \
      int in_ = cbase + 64 + lane;                                   \
      if (in_ > ce) in_ = ce;                                        \
      chN = bucket[in_];                                             \
    }                                                                \
    int t1_ = (BASE) + 1; if (t1_ > ce) t1_ = ce;                    \
    int t2_ = (BASE) + 2; if (t2_ > ce) t2_ = ce;                    \
    int t3_ = (BASE) + 3; if (t3_ > ce) t3_ = ce;                    \
    const int j0_ = t0_ - cbase, j1_ = t1_ - cbase;                  \
    const int j2_ = t2_ - cbase, j3_ = t3_ - cbase;                  \
    r##P##0 = __shfl(chC.x, j0_); v##P##0 = __shfl(chC.y, j0_);      \
    r##P##1 = __shfl(chC.x, j1_); v##P##1 = __shfl(chC.y, j1_);      \
    r##P##2 = __shfl(chC.x, j2_); v##P##2 = __shfl(chC.y, j2_);      \
    r##P##3 = __shfl(chC.x, j3_); v##P##3 = __shfl(chC.y, j3_);      \
    y##P##0 = Xl[(r##P##0 & 0x1FFFFFu) << 6];                        \
    y##P##1 = Xl[(r##P##1 & 0x1FFFFFu) << 6];                        \
    y##P##2 = Xl[(r##P##2 & 0x1FFFFFu) << 6];                        \
    y##P##3 = Xl[(r##P##3 & 0x1FFFFFu) << 6];                        \
  } while (0)

  if (s0 < e8) {
    const int ce = e8 - 1;
    // chunk double buffer: per-lane 8B record load covers 64 edges
    int cbase = s0;
    uint2 chC, chN;
    {
      int i0 = cbase + lane;
      if (i0 > ce) i0 = ce;
      chC = bucket[i0];
      int i1 = cbase + 64 + lane;
      if (i1 > ce) i1 = ce;
      chN = bucket[i1];
    }
    unsigned rA0, rA1, rA2, rA3, vA0, vA1, vA2, vA3, yA0, yA1, yA2, yA3;
    unsigned rB0, rB1, rB2, rB3, vB0, vB1, vB2, vB3, yB0, yB1, yB2, yB3;
    unsigned rC0, rC1, rC2, rC3, vC0, vC1, vC2, vC3, yC0, yC1, yC2, yC3;
    unsigned rD0, rD1, rD2, rD3, vD0, vD1, vD2, vD3, yD0, yD1, yD2, yD3;
    LOADG(A, s0);
    LOADG(B, s0 + 4);
    LOADG(C, s0 + 8);
    int gi = s0;
    while (gi < e8) {
      LOADG(D, gi + 12);
      ACCT(gi, rA0, vA0, yA0);
      ACCT(gi + 1, rA1, vA1, yA1);
      ACCT(gi + 2, rA2, vA2, yA2);
      ACCT(gi + 3, rA3, vA3, yA3);
      LOADG(A, gi + 16);
      ACCT(gi + 4, rB0, vB0, yB0);
      ACCT(gi + 5, rB1, vB1, yB1);
      ACCT(gi + 6, rB2, vB2, yB2);
      ACCT(gi + 7, rB3, vB3, yB3);
      LOADG(B, gi + 20);
      ACCT(gi + 8, rC0, vC0, yC0);
      ACCT(gi + 9, rC1, vC1, yC1);
      ACCT(gi + 10, rC2, vC2, yC2);
      ACCT(gi + 11, rC3, vC3, yC3);
      LOADG(C, gi + 24);
      ACCT(gi + 12, rD0, vD0, yD0);
      ACCT(gi + 13, rD1, vD1, yD1);
      ACCT(gi + 14, rD2, vD2, yD2);
      ACCT(gi + 15, rD3, vD3, yD3);
      gi += 16;
    }
  }
  while (row < 8) FLUSH();  // trailing (and fully-empty) rows

  __syncthreads();

  // ---- phase 2: 16x128 output tile via 16x16x32 MFMA, K=512 ----
  // wave covers output cols wave*64 .. +63 (4 col-fragments)
  const int q = lane >> 4, r16 = lane & 15;
  const int wn = wave * 64;
  const floatx4 zero = {0.f, 0.f, 0.f, 0.f};
  floatx4 acc[4];
  acc[0] = zero; acc[1] = zero; acc[2] = zero; acc[3] = zero;

#pragma unroll 4
  for (int k0 = 0; k0 < 512; k0 += 32) {
    int ka = k0 + q * 8;
    short8 af = *(const short8*)&aggS[r16][ka];
    short8 bfv[4];
#pragma unroll
    for (int j = 0; j < 4; ++j)
      bfv[j] = *(const short8*)(W2T + (size_t)(wn + j * 16 + r16) * 512 + ka);
#pragma unroll
    for (int j = 0; j < 4; ++j)
      acc[j] = __builtin_amdgcn_mfma_f32_16x16x32_bf16(af, bfv[j], acc[j], 0, 0, 0);
  }

  // epilogue: C/D layout col=lane&15, row=(lane>>4)*4+p  [m89/m91-verified]
#pragma unroll
  for (int j = 0; j < 4; ++j) {
#pragma unroll
    for (int p = 0; p < 4; ++p) {
      int prow = q * 4 + p;
      int col = wn + j * 16 + r16;
      int grow = blockIdx.x * 16 + prow;
      if (grow < Nn) out[(size_t)grow * 128 + col] = acc[j][p];
    }
  }
}

extern "C" void kernel_launch(void* const* d_in, const int* in_sizes, int n_in,
                              void* d_out, int out_size, void* d_ws, size_t ws_size,
                              hipStream_t stream) {
  const float* X = (const float*)d_in[0];
  const int* esrc = (const int*)d_in[1];
  const int* edst = (const int*)d_in[2];
  const int* erel = (const int*)d_in[3];
  const float* eval_ = (const float*)d_in[4];
  const float* w_bases = (const float*)d_in[5];
  const float* w_rel = (const float*)d_in[6];
  const int Nn = in_sizes[0] / D_IN;  // 100000
  const int E = in_sizes[1];          // 640000

  char* ws = (char*)d_ws;
  size_t off = 0;
  auto alloc = [&](size_t bytes) -> char* {
    char* p = ws + off;
    off += (bytes + 255) & ~(size_t)255;
    return p;
  };
  unsigned short* Xb = (unsigned short*)alloc((size_t)Nn * D_IN * 2);     // 25.6 MB
  unsigned short* W2T = (unsigned short*)alloc((size_t)128 * 512 * 2);    // 128 KB
  int* counts = (int*)alloc((size_t)Nn * 4);
  int* cursor = (int*)alloc((size_t)Nn * 4);
  int* offsets = (int*)alloc((size_t)(Nn + 1) * 4);
  int* localsc = (int*)alloc((size_t)Nn * 4);
  int* bsum = (int*)alloc(4096);
  uint2* bucket = (uint2*)alloc((size_t)E * 8);                           // 5.1 MB
  (void)ws_size;

  int n4 = Nn * D_IN / 4;  // 3.2M
  int nc4 = Nn / 4;        // counts as uint4
  k_prep<<<(n4 + 255) / 256, 256, 0, stream>>>((const float4*)X, (ushort4*)Xb, n4,
                                               w_bases, W2T, (uint4*)counts, nc4);

  k_count<<<(E + 255) / 256, 256, 0, stream>>>(edst, counts, E);
  int nb = (Nn + 255) / 256;
  k_scan1<<<nb, 256, 0, stream>>>(counts, localsc, bsum, Nn);
  k_scan23<<<nb, 256, 0, stream>>>(localsc, bsum, offsets, cursor, Nn, E);
  k_bucket<<<(E + 255) / 256, 256, 0, stream>>>(esrc, edst, erel, eval_, cursor, bucket, E);

  // fused aggregation + transform: 2-wave blocks, 16 dsts each
  k_agg_gemm<<<(Nn + 15) / 16, 128, 0, stream>>>(bucket, offsets, w_rel,
                                                 (const unsigned*)Xb, W2T,
                                                 (float*)d_out, Nn);
}

// Round 5
// 254.900 us; speedup vs baseline: 1.1390x; 1.1390x over previous
//
#include <hip/hip_runtime.h>
#include <stdint.h>

#define D_IN 128
#define D_OUT 128
#define NREL 8
#define NBASE 4

typedef __attribute__((ext_vector_type(8))) short short8;
typedef __attribute__((ext_vector_type(4))) float floatx4;
typedef __attribute__((ext_vector_type(2))) float floatx2;

__device__ __forceinline__ unsigned short f2bf(float f) {
  unsigned int u = __float_as_uint(f);
  u += 0x7fffu + ((u >> 16) & 1u);
  return (unsigned short)(u >> 16);
}
__device__ __forceinline__ unsigned pack2bf(float lo, float hi) {
  return (unsigned)f2bf(lo) | ((unsigned)f2bf(hi) << 16);
}
__device__ __forceinline__ float bflo(unsigned int u) { return __uint_as_float(u << 16); }
__device__ __forceinline__ float bfhi(unsigned int u) { return __uint_as_float(u & 0xffff0000u); }

// ---------- 1) prep: cast X fp32->bf16 + build W2T + count (counts pre-zeroed
// by hipMemsetAsync) ----------
// W2T[o][c] = w_bases[b][k][o], c = k*4+b  (bf16, [128][512])
__global__ void k_prep(const float4* __restrict__ X, ushort4* __restrict__ Xb, int n4,
                       const float* __restrict__ w_bases, unsigned short* __restrict__ W2T,
                       const int* __restrict__ edst, int* __restrict__ counts, int E) {
  int i = blockIdx.x * blockDim.x + threadIdx.x;
  if (i < n4) {
    float4 v = X[i];
    ushort4 o;
    o.x = f2bf(v.x); o.y = f2bf(v.y); o.z = f2bf(v.z); o.w = f2bf(v.w);
    Xb[i] = o;
  }
  if (i < 128 * 512) {
    int o = i >> 9, c = i & 511;
    int k = c >> 2, b = c & 3;
    W2T[i] = f2bf(w_bases[(b * D_IN + k) * D_OUT + o]);
  }
  if (i < E) atomicAdd(&counts[edst[i]], 1);
}

// ---------- 2) CSR build ----------
__global__ void k_scan1(const int* __restrict__ counts, int* __restrict__ localsc,
                        int* __restrict__ bsum, int Nn) {
  __shared__ int s[256];
  int i = blockIdx.x * 256 + threadIdx.x;
  int v = (i < Nn) ? counts[i] : 0;
  s[threadIdx.x] = v;
  __syncthreads();
  for (int off = 1; off < 256; off <<= 1) {
    int t = 0;
    if (threadIdx.x >= off) t = s[threadIdx.x - off];
    __syncthreads();
    s[threadIdx.x] += t;
    __syncthreads();
  }
  if (i < Nn) localsc[i] = s[threadIdx.x] - v;
  if (threadIdx.x == 255) bsum[blockIdx.x] = s[255];
}

// fused scan2+scan3: each block redundantly reduces bsum[0..blockIdx.x) (tiny)
__global__ void k_scan23(const int* __restrict__ localsc, const int* __restrict__ bsum,
                         int* __restrict__ offsets, int* __restrict__ cursor, int Nn, int E) {
  __shared__ int red[256];
  int acc = 0;
  for (int j = threadIdx.x; j < blockIdx.x; j += 256) acc += bsum[j];
  red[threadIdx.x] = acc;
  __syncthreads();
  for (int off = 128; off > 0; off >>= 1) {
    if (threadIdx.x < off) red[threadIdx.x] += red[threadIdx.x + off];
    __syncthreads();
  }
  int pref = red[0];
  int i = blockIdx.x * 256 + threadIdx.x;
  if (i < Nn) {
    int v = localsc[i] + pref;
    offsets[i] = v;
    cursor[i] = v;
  }
  if (i == 0) offsets[Nn] = E;
}

// compact 8B record: (src | rel<<21, val) — scattered write is 8B not 20B
__global__ void k_bucket(const int* __restrict__ src, const int* __restrict__ dst,
                         const int* __restrict__ rel, const float* __restrict__ val,
                         int* __restrict__ cursor, uint2* __restrict__ bucket, int E) {
  int i = blockIdx.x * blockDim.x + threadIdx.x;
  if (i >= E) return;
  int d = dst[i];
  int pos = atomicAdd(&cursor[d], 1);
  bucket[pos] = make_uint2((unsigned)src[i] | ((unsigned)rel[i] << 21), __float_as_uint(val[i]));
}

// ---------- 3) fused: per-dst basis aggregation (LDS) + MFMA transform ----------
// Block = 4 waves, 32 dst rows (33.8KB LDS -> 4 blocks/CU = 16 waves/CU).
// __launch_bounds__(256,4): VGPR cap 128 == LDS-imposed occupancy, so the
// depth-4 pipeline state (16 in-flight gathers/wave) stays in registers.
// [R4 lesson: plain launch_bounds targeted 8 waves/EU -> 60 VGPR -> compiler
// sank the gathers and collapsed the pipeline.]
// Wave w owns dsts [w*8, w*8+8) = ONE contiguous bucket range; edge records
// chunk-loaded cooperatively (64/load, double-buffered, __shfl distribute);
// the only vmcnt ops in the hot loop are the X gathers themselves.
__global__ __launch_bounds__(256, 4)
void k_agg_gemm(const uint2* __restrict__ bucket, const int* __restrict__ offsets,
                const float* __restrict__ w_rel_g, const unsigned* __restrict__ Xb2,
                const unsigned short* __restrict__ W2T, float* __restrict__ out, int Nn) {
  __shared__ __align__(16) unsigned short aggS[32][520];  // pitch 520: 2-way alias (free)
  __shared__ __align__(16) float wrS[NREL * NBASE];
  if (threadIdx.x < NREL * NBASE) wrS[threadIdx.x] = w_rel_g[threadIdx.x];
  __syncthreads();

  const int wave = threadIdx.x >> 6, lane = threadIdx.x & 63;
  const int d0 = blockIdx.x * 32 + wave * 8;
  const unsigned* __restrict__ Xl = Xb2 + lane;
  const floatx2 zf2 = {0.f, 0.f};

  // lane l (0..8) loads offsets[d0+l]; readlane -> SGPR bounds
  int oidx = d0 + (lane < 8 ? lane : 8);
  if (oidx > Nn) oidx = Nn;
  const int offv = offsets[oidx];
  const int s0 = __builtin_amdgcn_readlane(offv, 0);
  const int e8 = __builtin_amdgcn_readlane(offv, 8);

  floatx2 a0 = zf2, a1 = zf2, a2 = zf2, a3 = zf2;
  int row = 0;
  int bnd = __builtin_amdgcn_readlane(offv, 1);

#define FLUSH()                                                      \
  do {                                                               \
    uint4 o_;                                                        \
    o_.x = pack2bf(a0.x, a1.x);                                      \
    o_.y = pack2bf(a2.x, a3.x);                                      \
    o_.z = pack2bf(a0.y, a1.y);                                      \
    o_.w = pack2bf(a2.y, a3.y);                                      \
    *(uint4*)&aggS[wave * 8 + row][lane * 8] = o_;                   \
    a0 = zf2; a1 = zf2; a2 = zf2; a3 = zf2;                          \
    ++row;                                                           \
    bnd = (row < 8) ? __builtin_amdgcn_readlane(offv, row + 1)       \
                    : 0x7fffffff;                                    \
  } while (0)

  // ACCT: R = packed (src|rel<<21), V = val bits, Y = gathered 2xbf16
#define ACCT(EI, R, V, Y)                                            \
  do {                                                               \
    if ((EI) < e8) {                                                 \
      while ((EI) == bnd) FLUSH();                                   \
      const float4 w_ = *(const float4*)&wrS[((R) >> 21) * 4];       \
      const float val_ = __uint_as_float(V);                         \
      const float c0_ = val_ * w_.x, c1_ = val_ * w_.y;              \
      const float c2_ = val_ * w_.z, c3_ = val_ * w_.w;              \
      floatx2 x_;                                                    \
      x_.x = bflo(Y);                                                \
      x_.y = bfhi(Y);                                                \
      a0 += c0_ * x_;                                                \
      a1 += c1_ * x_;                                                \
      a2 += c2_ * x_;                                                \
      a3 += c3_ * x_;                                                \
    }                                                                \
  } while (0)

  // LOADG: rotate chunk if needed, shuffle 4 records out, issue 4 gathers.
  // All indices clamped to ce so over-issue past e8 is safe (ACCT guards).
  // Invariant: group bases === s0 (mod 4), chunk bounds === s0 (mod 64)
  // -> a group never straddles a chunk; prefetch distance 24 < 64 means a
  // single rotation per LOADG suffices.
#define LOADG(P, BASE)                                               \
  do {                                                               \
    int t0_ = (BASE); if (t0_ > ce) t0_ = ce;                        \
    if (t0_ - cbase >= 64) {                                         \
      cbase += 64;                                                   \
      chC = chN;                                                     \
      int in_ = cbase + 64 + lane;                                   \
      if (in_ > ce) in_ = ce;                                        \
      chN = bucket[in_];                                             \
    }                                                                \
    int t1_ = (BASE) + 1; if (t1_ > ce) t1_ = ce;                    \
    int t2_ = (BASE) + 2; if (t2_ > ce) t2_ = ce;                    \
    int t3_ = (BASE) + 3; if (t3_ > ce) t3_ = ce;                    \
    const int j0_ = t0_ - cbase, j1_ = t1_ - cbase;                  \
    const int j2_ = t2_ - cbase, j3_ = t3_ - cbase;                  \
    r##P##0 = __shfl(chC.x, j0_); v##P##0 = __shfl(chC.y, j0_);      \
    r##P##1 = __shfl(chC.x, j1_); v##P##1 = __shfl(chC.y, j1_);      \
    r##P##2 = __shfl(chC.x, j2_); v##P##2 = __shfl(chC.y, j2_);      \
    r##P##3 = __shfl(chC.x, j3_); v##P##3 = __shfl(chC.y, j3_);      \
    y##P##0 = Xl[(r##P##0 & 0x1FFFFFu) << 6];                        \
    y##P##1 = Xl[(r##P##1 & 0x1FFFFFu) << 6];                        \
    y##P##2 = Xl[(r##P##2 & 0x1FFFFFu) << 6];                        \
    y##P##3 = Xl[(r##P##3 & 0x1FFFFFu) << 6];                        \
  } while (0)

  if (s0 < e8) {
    const int ce = e8 - 1;
    // chunk double buffer: per-lane 8B record load covers 64 edges
    int cbase = s0;
    uint2 chC, chN;
    {
      int i0 = cbase + lane;
      if (i0 > ce) i0 = ce;
      chC = bucket[i0];
      int i1 = cbase + 64 + lane;
      if (i1 > ce) i1 = ce;
      chN = bucket[i1];
    }
    unsigned rA0, rA1, rA2, rA3, vA0, vA1, vA2, vA3, yA0, yA1, yA2, yA3;
    unsigned rB0, rB1, rB2, rB3, vB0, vB1, vB2, vB3, yB0, yB1, yB2, yB3;
    unsigned rC0, rC1, rC2, rC3, vC0, vC1, vC2, vC3, yC0, yC1, yC2, yC3;
    unsigned rD0, rD1, rD2, rD3, vD0, vD1, vD2, vD3, yD0, yD1, yD2, yD3;
    LOADG(A, s0);
    LOADG(B, s0 + 4);
    LOADG(C, s0 + 8);
    int gi = s0;
    while (gi < e8) {
      LOADG(D, gi + 12);
      ACCT(gi, rA0, vA0, yA0);
      ACCT(gi + 1, rA1, vA1, yA1);
      ACCT(gi + 2, rA2, vA2, yA2);
      ACCT(gi + 3, rA3, vA3, yA3);
      LOADG(A, gi + 16);
      ACCT(gi + 4, rB0, vB0, yB0);
      ACCT(gi + 5, rB1, vB1, yB1);
      ACCT(gi + 6, rB2, vB2, yB2);
      ACCT(gi + 7, rB3, vB3, yB3);
      LOADG(B, gi + 20);
      ACCT(gi + 8, rC0, vC0, yC0);
      ACCT(gi + 9, rC1, vC1, yC1);
      ACCT(gi + 10, rC2, vC2, yC2);
      ACCT(gi + 11, rC3, vC3, yC3);
      LOADG(C, gi + 24);
      ACCT(gi + 12, rD0, vD0, yD0);
      ACCT(gi + 13, rD1, vD1, yD1);
      ACCT(gi + 14, rD2, vD2, yD2);
      ACCT(gi + 15, rD3, vD3, yD3);
      gi += 16;
    }
  }
  while (row < 8) FLUSH();  // trailing (and fully-empty) rows

  __syncthreads();

  // ---- phase 2: 32x128 output tile via 16x16x32 MFMA, K=512 ----
  const int q = lane >> 4, r16 = lane & 15;
  const int wn = wave * 32;
  const floatx4 zero = {0.f, 0.f, 0.f, 0.f};
  floatx4 acc[2][2];
  acc[0][0] = zero; acc[0][1] = zero; acc[1][0] = zero; acc[1][1] = zero;

#pragma unroll 4
  for (int k0 = 0; k0 < 512; k0 += 32) {
    int ka = k0 + q * 8;
    short8 af[2], bfv[2];
    af[0] = *(const short8*)&aggS[r16][ka];
    af[1] = *(const short8*)&aggS[16 + r16][ka];
    bfv[0] = *(const short8*)(W2T + (size_t)(wn + r16) * 512 + ka);
    bfv[1] = *(const short8*)(W2T + (size_t)(wn + 16 + r16) * 512 + ka);
#pragma unroll
    for (int i = 0; i < 2; ++i)
#pragma unroll
      for (int j = 0; j < 2; ++j)
        acc[i][j] = __builtin_amdgcn_mfma_f32_16x16x32_bf16(af[i], bfv[j], acc[i][j], 0, 0, 0);
  }

  // epilogue: C/D layout col=lane&15, row=(lane>>4)*4+p  [m89/m91-verified]
#pragma unroll
  for (int i = 0; i < 2; ++i) {
#pragma unroll
    for (int j = 0; j < 2; ++j) {
#pragma unroll
      for (int p = 0; p < 4; ++p) {
        int prow = i * 16 + q * 4 + p;
        int col = wn + j * 16 + r16;
        int grow = blockIdx.x * 32 + prow;
        if (grow < Nn) out[(size_t)grow * 128 + col] = acc[i][j][p];
      }
    }
  }
}

extern "C" void kernel_launch(void* const* d_in, const int* in_sizes, int n_in,
                              void* d_out, int out_size, void* d_ws, size_t ws_size,
                              hipStream_t stream) {
  const float* X = (const float*)d_in[0];
  const int* esrc = (const int*)d_in[1];
  const int* edst = (const int*)d_in[2];
  const int* erel = (const int*)d_in[3];
  const float* eval_ = (const float*)d_in[4];
  const float* w_bases = (const float*)d_in[5];
  const float* w_rel = (const float*)d_in[6];
  const int Nn = in_sizes[0] / D_IN;  // 100000
  const int E = in_sizes[1];          // 640000

  char* ws = (char*)d_ws;
  size_t off = 0;
  auto alloc = [&](size_t bytes) -> char* {
    char* p = ws + off;
    off += (bytes + 255) & ~(size_t)255;
    return p;
  };
  unsigned short* Xb = (unsigned short*)alloc((size_t)Nn * D_IN * 2);     // 25.6 MB
  unsigned short* W2T = (unsigned short*)alloc((size_t)128 * 512 * 2);    // 128 KB
  int* counts = (int*)alloc((size_t)Nn * 4);
  int* cursor = (int*)alloc((size_t)Nn * 4);
  int* offsets = (int*)alloc((size_t)(Nn + 1) * 4);
  int* localsc = (int*)alloc((size_t)Nn * 4);
  int* bsum = (int*)alloc(4096);
  uint2* bucket = (uint2*)alloc((size_t)E * 8);                           // 5.1 MB
  (void)ws_size;

  int n4 = Nn * D_IN / 4;  // 3.2M
  hipMemsetAsync(counts, 0, (size_t)Nn * 4, stream);
  k_prep<<<(n4 + 255) / 256, 256, 0, stream>>>((const float4*)X, (ushort4*)Xb, n4,
                                               w_bases, W2T, edst, counts, E);

  int nb = (Nn + 255) / 256;
  k_scan1<<<nb, 256, 0, stream>>>(counts, localsc, bsum, Nn);
  k_scan23<<<nb, 256, 0, stream>>>(localsc, bsum, offsets, cursor, Nn, E);
  k_bucket<<<(E + 255) / 256, 256, 0, stream>>>(esrc, edst, erel, eval_, cursor, bucket, E);

  // fused aggregation + transform: 4-wave blocks, 32 dsts each
  k_agg_gemm<<<(Nn + 31) / 32, 256, 0, stream>>>(bucket, offsets, w_rel,
                                                 (const unsigned*)Xb, W2T,
                                                 (float*)d_out, Nn);
}